// Round 4
// baseline (351.527 us; speedup 1.0000x reference)
//
#include <hip/hip_runtime.h>

#define NN 50000
#define NE 800000
#define NB 196   // (NN+255)/256
#define K1B 782  // (NN+63)/64

typedef __attribute__((ext_vector_type(8))) short bf16x8;
typedef __attribute__((ext_vector_type(4))) float f32x4;
typedef __attribute__((ext_vector_type(2))) _Float16 h2f;
typedef __attribute__((ext_vector_type(8))) _Float16 f16x8v;

__device__ __forceinline__ int rfl(int v) { return __builtin_amdgcn_readfirstlane(v); }

__device__ __forceinline__ unsigned short bfb(float x) {
    union { float f; unsigned u; } v; v.f = x;
    unsigned r = v.u + 0x7FFFu + ((v.u >> 16) & 1u);
    return (unsigned short)(r >> 16);
}
__device__ __forceinline__ unsigned pkbf(float lo, float hi) {
    return ((unsigned)bfb(hi) << 16) | (unsigned)bfb(lo);
}
__device__ __forceinline__ unsigned pkh2(float a, float b) {
    union { h2f h; unsigned u; } x;
    x.h.x = (_Float16)a; x.h.y = (_Float16)b;
    return x.u;
}
__device__ __forceinline__ unsigned short h16(float x) {
    union { _Float16 h; unsigned short s; } u; u.h = (_Float16)x; return u.s;
}

// 2^x via single v_exp_f32 (input pre-scaled by log2(e) upstream).
__device__ __forceinline__ float exp2_hw(float x) {
    float r;
    asm("v_exp_f32 %0, %1" : "=v"(r) : "v"(x));
    return r;
}

// ---------------------------------------------------------------------------
// K0 (small prep): bf16-transpose MLP/node weights, f16 W_e in MFMA-B layout
// (Wef[ch*16 + k] = f16(W_e[k][ch])), zero deg, row_start[NN]=NE.
// ---------------------------------------------------------------------------
__global__ __launch_bounds__(256) void k0_prep(
    const float* __restrict__ W_l, const float* __restrict__ W_r,
    const float* __restrict__ res_W, const float* __restrict__ W0,
    const float* __restrict__ W1, const float* __restrict__ W_e,
    unsigned short* __restrict__ Wtl, unsigned short* __restrict__ Wtr,
    unsigned short* __restrict__ Wtres, unsigned short* __restrict__ Wt0,
    unsigned short* __restrict__ Wt1,
    unsigned short* __restrict__ Wef,
    int* __restrict__ deg, int* __restrict__ row_start)
{
    const int t0 = blockIdx.x * 256 + threadIdx.x;
    if (t0 < 24576) { int n = t0 / 192, k = t0 - n * 192; Wt0[t0] = bfb(W0[k * 128 + n]); }
    if (t0 < 16384) { int n = t0 >> 7, k = t0 & 127; Wt1[t0] = bfb(W1[k * 128 + n]); }
    if (t0 < 8192) {
        int n = t0 >> 6, k = t0 & 63;
        Wtl[t0]   = bfb(W_l[k * 128 + n]);
        Wtr[t0]   = bfb(W_r[k * 128 + n]);
        Wtres[t0] = bfb(res_W[k * 128 + n]);
    }
    if (t0 < 2048) {  // Wef[ch*16 + k] = f16(W_e[k][ch])
        int ch = t0 >> 4, k = t0 & 15;
        Wef[t0] = h16(W_e[k * 128 + ch]);
    }
    if (t0 < NN) deg[t0] = 0;
    if (t0 == 0) row_start[NN] = NE;
}

// ---------------------------------------------------------------------------
// KA (fused): blocks [0,K1B) do the MFMA node transforms (x_l -> packed f16,
// x_r, ident); blocks [K1B, ...) do degree count AND record per-edge rank.
// ---------------------------------------------------------------------------
__global__ __launch_bounds__(256, 4) void ka_nodes_degree(
    const float* __restrict__ nf,
    const unsigned short* __restrict__ Wtl, const float* __restrict__ b_l,
    const unsigned short* __restrict__ Wtr, const float* __restrict__ b_r,
    const unsigned short* __restrict__ Wtres, const float* __restrict__ res_b,
    const float* __restrict__ res_g, const float* __restrict__ res_beta,
    unsigned* __restrict__ xlp, float* __restrict__ x_r, float* __restrict__ ident,
    const int* __restrict__ eidx, int* __restrict__ deg, int* __restrict__ rank)
{
    if (blockIdx.x >= K1B) {
        int e = (blockIdx.x - K1B) * 256 + threadIdx.x;
        if (e < NE) rank[e] = atomicAdd(deg + eidx[NE + e], 1);
        return;
    }
    __shared__ __align__(16) unsigned As32[64 * 36];
    const int tid = threadIdx.x;
    const int node0 = blockIdx.x * 64;

    for (int i = tid; i < 64 * 32; i += 256) {
        int n = i >> 5, c2 = i & 31;
        int gn = node0 + n;
        float2 v = make_float2(0.f, 0.f);
        if (gn < NN) v = *(const float2*)(nf + gn * 64 + 2 * c2);
        As32[n * 36 + c2] = pkbf(v.x, v.y);
    }
    __syncthreads();

    const int lane = tid & 63, w = tid >> 6;
    const int c = lane & 15, ko = lane >> 4;
    const unsigned short* As = (const unsigned short*)As32;
    bf16x8 a0 = *(const bf16x8*)(As + (w * 16 + c) * 72 + 0 * 32 + ko * 8);
    bf16x8 a1 = *(const bf16x8*)(As + (w * 16 + c) * 72 + 1 * 32 + ko * 8);
    const int lrow0 = node0 + w * 16 + 4 * ko;

    #pragma unroll
    for (int p = 0; p < 3; ++p) {
        const unsigned short* Wt = (p == 0) ? Wtl : (p == 1) ? Wtr : Wtres;
        f32x4 acc[8];
        #pragma unroll
        for (int nt = 0; nt < 8; ++nt) acc[nt] = f32x4{0.f, 0.f, 0.f, 0.f};
        #pragma unroll
        for (int nt = 0; nt < 8; ++nt) {
            bf16x8 bf0 = *(const bf16x8*)(Wt + (nt * 16 + c) * 64 + 0 * 32 + ko * 8);
            acc[nt] = __builtin_amdgcn_mfma_f32_16x16x32_bf16(a0, bf0, acc[nt], 0, 0, 0);
            bf16x8 bf1 = *(const bf16x8*)(Wt + (nt * 16 + c) * 64 + 1 * 32 + ko * 8);
            acc[nt] = __builtin_amdgcn_mfma_f32_16x16x32_bf16(a1, bf1, acc[nt], 0, 0, 0);
        }
        if (p == 0) {
            float bv[8];
            #pragma unroll
            for (int nt = 0; nt < 8; ++nt) bv[nt] = b_l[nt * 16 + c];
            #pragma unroll
            for (int reg = 0; reg < 4; ++reg) {
                int row = lrow0 + reg;
                #pragma unroll
                for (int nt = 0; nt < 8; ++nt) {
                    float v = acc[nt][reg] + bv[nt];
                    float v2 = __shfl_xor(v, 1, 64);
                    if (row < NN && (lane & 1) == 0)
                        xlp[row * 64 + nt * 8 + (c >> 1)] = pkh2(v, v2);
                }
            }
        } else if (p == 1) {
            float bv[8];
            #pragma unroll
            for (int nt = 0; nt < 8; ++nt) bv[nt] = b_r[nt * 16 + c];
            #pragma unroll
            for (int reg = 0; reg < 4; ++reg) {
                int row = lrow0 + reg;
                if (row < NN) {
                    #pragma unroll
                    for (int nt = 0; nt < 8; ++nt)
                        x_r[row * 128 + nt * 16 + c] = acc[nt][reg] + bv[nt];
                }
            }
        } else {
            float bv[8], gv[8], tv[8];
            #pragma unroll
            for (int nt = 0; nt < 8; ++nt) {
                bv[nt] = res_b[nt * 16 + c];
                gv[nt] = res_g[nt * 16 + c];
                tv[nt] = res_beta[nt * 16 + c];
            }
            #pragma unroll
            for (int reg = 0; reg < 4; ++reg) {
                float sum = 0.f, sq = 0.f, hv[8];
                #pragma unroll
                for (int nt = 0; nt < 8; ++nt) {
                    float v = acc[nt][reg] + bv[nt];
                    hv[nt] = v; sum += v; sq += v * v;
                }
                #pragma unroll
                for (int m = 1; m <= 8; m <<= 1) {
                    sum += __shfl_xor(sum, m, 64);
                    sq  += __shfl_xor(sq, m, 64);
                }
                float mean = sum * (1.f / 128.f);
                float inv  = rsqrtf(sq * (1.f / 128.f) - mean * mean + 1e-5f);
                int row = lrow0 + reg;
                if (row < NN) {
                    #pragma unroll
                    for (int nt = 0; nt < 8; ++nt)
                        ident[row * 128 + nt * 16 + c] =
                            (hv[nt] - mean) * inv * gv[nt] + tv[nt];
                }
            }
        }
    }
}

// ---------------------------------------------------------------------------
// K3a: per-block degree sums.
// ---------------------------------------------------------------------------
__global__ __launch_bounds__(256) void k3a_blocksum(
    const int* __restrict__ deg, int* __restrict__ bsum)
{
    __shared__ int ws[4];
    int i = blockIdx.x * 256 + threadIdx.x;
    int v = (i < NN) ? deg[i] : 0;
    #pragma unroll
    for (int m = 32; m >= 1; m >>= 1) v += __shfl_xor(v, m, 64);
    if ((threadIdx.x & 63) == 0) ws[threadIdx.x >> 6] = v;
    __syncthreads();
    if (threadIdx.x == 0) bsum[blockIdx.x] = ws[0] + ws[1] + ws[2] + ws[3];
}

// ---------------------------------------------------------------------------
// K3c: block-local scan + prefix of bsum -> row_start.
// ---------------------------------------------------------------------------
__global__ __launch_bounds__(256) void k3c_apply(
    const int* __restrict__ deg, const int* __restrict__ bsum,
    int* __restrict__ row_start)
{
    __shared__ int wsum[4];
    __shared__ int roff[4];
    const int tid = threadIdx.x, lane = tid & 63, wid = tid >> 6;
    int bv = (tid < blockIdx.x) ? bsum[tid] : 0;   // blockIdx.x <= 195 < 256
    #pragma unroll
    for (int m = 32; m >= 1; m >>= 1) bv += __shfl_xor(bv, m, 64);
    if (lane == 0) roff[wid] = bv;

    int i = blockIdx.x * 256 + tid;
    int v = (i < NN) ? deg[i] : 0;
    int sc = v;
    #pragma unroll
    for (int m = 1; m < 64; m <<= 1) {
        int t = __shfl_up(sc, m, 64);
        if (lane >= m) sc += t;
    }
    if (lane == 63) wsum[wid] = sc;
    __syncthreads();
    int off = roff[0] + roff[1] + roff[2] + roff[3];
    for (int w = 0; w < wid; ++w) off += wsum[w];
    int excl = off + sc - v;
    if (i < NN) row_start[i] = excl;
}

// ---------------------------------------------------------------------------
// K4: pure scatter (no atomics): pos = row_start[dst] + rank[e].
// ---------------------------------------------------------------------------
__global__ __launch_bounds__(256) void k4_scatter(
    const int* __restrict__ eidx, const int* __restrict__ row_start,
    const int* __restrict__ rank, int2* __restrict__ csr_es)
{
    int e = blockIdx.x * 256 + threadIdx.x;
    if (e >= NE) return;
    int dst = eidx[NE + e];
    csr_es[row_start[dst] + rank[e]] = make_int2(e, eidx[e]);
}

// ---------------------------------------------------------------------------
// K5 (MFMA): fused GATv2 attention + aggregation. One wave per node.
// Per 16-edge batch: e-transform = 8x mfma_f32_16x16x32_f16 with
//   A[edge=lane&15][k] = f16(ef row, loaded f32 direct, K zero-padded 16->32),
//   B[t] lane&15 = channel cq*8+t (head = cq>>2 constant per lane),
//   acc initialized to x_r (folds the x_r add into the MFMA C).
// D layout: col(=channel idx cq)=lane&15, edge row = (lane>>4)*4+reg.
// Softmax per head: in-lane accumulate over 8 channels + 2 quad-perm DPP
// adds. x_l gather: one 16B contiguous load per (group,reg) -> full row
// coalesced per 16-lane group. exp via v_exp_f32 (att pre-scaled log2e).
// ---------------------------------------------------------------------------
__global__ __launch_bounds__(256, 3) void k5_attn_aggregate(
    const int2* __restrict__ csr_es, const int* __restrict__ row_start,
    const float* __restrict__ ef, const unsigned short* __restrict__ Wef,
    const float* __restrict__ att,
    const unsigned* __restrict__ xlp, const float* __restrict__ x_r,
    const float* __restrict__ gat_bias,
    float* __restrict__ gat_out)
{
    const int lane = threadIdx.x & 63;
    const int node = (blockIdx.x * 256 + threadIdx.x) >> 6;
    if (node >= NN) return;
    const int cq = lane & 15;        // A edge-row / D channel-col
    const int ko = lane >> 4;        // K-octet group / D edge-row group
    const int q4 = ko * 4;
    const int ch0 = cq * 8;          // this lane's channel base (one head)
    const bool kok = ko < 2;

    // B fragments: W_e columns (channel ch0+t), K zero-padded beyond 16.
    union BU { uint4 u; f16x8v h; };
    f16x8v B[8];
    #pragma unroll
    for (int t = 0; t < 8; ++t) {
        BU b; b.u = make_uint4(0u, 0u, 0u, 0u);
        if (kok) b.u = *(const uint4*)(Wef + (ch0 + t) * 16 + ko * 8);
        B[t] = b.h;
    }

    const float LOG2E = 1.44269504088896340736f;
    float attv[8], xrv[8];
    {
        float4 a0 = *(const float4*)(att + ch0);
        float4 a1 = *(const float4*)(att + ch0 + 4);
        attv[0] = a0.x * LOG2E; attv[1] = a0.y * LOG2E;
        attv[2] = a0.z * LOG2E; attv[3] = a0.w * LOG2E;
        attv[4] = a1.x * LOG2E; attv[5] = a1.y * LOG2E;
        attv[6] = a1.z * LOG2E; attv[7] = a1.w * LOG2E;
        float4 x0 = *(const float4*)(x_r + node * 128 + ch0);
        float4 x1 = *(const float4*)(x_r + node * 128 + ch0 + 4);
        xrv[0] = x0.x; xrv[1] = x0.y; xrv[2] = x0.z; xrv[3] = x0.w;
        xrv[4] = x1.x; xrv[5] = x1.y; xrv[6] = x1.z; xrv[7] = x1.w;
    }

    const int sj  = rfl(row_start[node]);
    const int epj = rfl(row_start[node + 1]);
    const unsigned short* __restrict__ xlus = (const unsigned short*)xlp;

    float den = 0.f;
    float n[8];
    #pragma unroll
    for (int t = 0; t < 8; ++t) n[t] = 0.f;

    union XU { uint4 u; _Float16 h[8]; };

    for (int base = sj; base < epj; base += 64) {
        const int cnt = min(64, epj - base);
        int pidx = base + lane;
        const int pmax = epj - 1;
        if (pidx > pmax) pidx = pmax;
        const int2 mc = csr_es[pidx];   // chunk's (eid, src): lane L = edge L
        const int nb = (cnt + 15) >> 4;

        for (int b = 0; b < nb; ++b) {
            // ---- A fragment: ef row of edge (b*16 + cq), f32 -> f16 ----
            int eid = __shfl(mc.x, b * 16 + cq, 64);
            f16x8v A = f16x8v{0, 0, 0, 0, 0, 0, 0, 0};
            if (kok) {
                const float4* er = (const float4*)(ef + (size_t)eid * 16 + ko * 8);
                float4 v0 = er[0], v1 = er[1];
                A[0] = (_Float16)v0.x; A[1] = (_Float16)v0.y;
                A[2] = (_Float16)v0.z; A[3] = (_Float16)v0.w;
                A[4] = (_Float16)v1.x; A[5] = (_Float16)v1.y;
                A[6] = (_Float16)v1.z; A[7] = (_Float16)v1.w;
            }

            // ---- src rows + x_l raw loads (4 edge-regs per group) ----
            int s0 = __shfl(mc.y, b * 16 + q4 + 0, 64);
            int s1 = __shfl(mc.y, b * 16 + q4 + 1, 64);
            int s2 = __shfl(mc.y, b * 16 + q4 + 2, 64);
            int s3 = __shfl(mc.y, b * 16 + q4 + 3, 64);
            XU xa, xb, xc, xd;
            xa.u = *(const uint4*)(xlus + s0 * 128 + ch0);
            xb.u = *(const uint4*)(xlus + s1 * 128 + ch0);
            xc.u = *(const uint4*)(xlus + s2 * 128 + ch0);
            xd.u = *(const uint4*)(xlus + s3 * 128 + ch0);

            // ---- MFMA: acc init = x_r (folds the x_r add) ----
            f32x4 acc[8];
            #pragma unroll
            for (int t = 0; t < 8; ++t)
                acc[t] = f32x4{xrv[t], xrv[t], xrv[t], xrv[t]};
            #pragma unroll
            for (int t = 0; t < 8; ++t)
                acc[t] = __builtin_amdgcn_mfma_f32_16x16x32_f16(A, B[t], acc[t], 0, 0, 0);

            // ---- epilogue per edge-reg ----
#define EPI(R, XR)                                                          \
            { float p = 0.f; float xlv[8];                                  \
              _Pragma("unroll")                                             \
              for (int t = 0; t < 8; ++t) {                                 \
                  float xl = (float)XR.h[t];                                \
                  xlv[t] = xl;                                              \
                  float m = acc[t][R] + xl;                                 \
                  p = fmaf(fmaxf(m, 0.2f * m), attv[t], p);                 \
              }                                                             \
              asm("v_add_f32 %0, %0, %0 quad_perm:[1,0,3,2] row_mask:0xf bank_mask:0xf" : "+v"(p)); \
              asm("v_add_f32 %0, %0, %0 quad_perm:[2,3,0,1] row_mask:0xf bank_mask:0xf" : "+v"(p)); \
              float ev = exp2_hw(p);                                        \
              ev = ((b * 16 + q4 + R) < cnt) ? ev : 0.f;                    \
              den += ev;                                                    \
              _Pragma("unroll")                                             \
              for (int t = 0; t < 8; ++t) n[t] = fmaf(ev, xlv[t], n[t]); }

            EPI(0, xa)
            EPI(1, xb)
            EPI(2, xc)
            EPI(3, xd)
#undef EPI
        }
    }

    // cross-group (edge-row group) reduction: 4 groups hold disjoint edges
    den += __shfl_xor(den, 16, 64);
    den += __shfl_xor(den, 32, 64);
    #pragma unroll
    for (int t = 0; t < 8; ++t) {
        n[t] += __shfl_xor(n[t], 16, 64);
        n[t] += __shfl_xor(n[t], 32, 64);
    }
    float rden = (den > 0.f) ? (1.f / den) : 0.f;
    if (lane < 16) {
        float4 g0 = *(const float4*)(gat_bias + ch0);
        float4 g1 = *(const float4*)(gat_bias + ch0 + 4);
        float4 o0, o1;
        o0.x = fmaf(n[0], rden, g0.x); o0.y = fmaf(n[1], rden, g0.y);
        o0.z = fmaf(n[2], rden, g0.z); o0.w = fmaf(n[3], rden, g0.w);
        o1.x = fmaf(n[4], rden, g1.x); o1.y = fmaf(n[5], rden, g1.y);
        o1.z = fmaf(n[6], rden, g1.z); o1.w = fmaf(n[7], rden, g1.w);
        *(float4*)(gat_out + node * 128 + ch0)     = o0;
        *(float4*)(gat_out + node * 128 + ch0 + 4) = o1;
    }
}

// ---------------------------------------------------------------------------
// K6 (MFMA): MLP + LN + residual add.  (unchanged)
// ---------------------------------------------------------------------------
__global__ __launch_bounds__(256, 4) void k6_mlp_mfma(
    const float* __restrict__ nf, const float* __restrict__ gat,
    const float* __restrict__ ident,
    const unsigned short* __restrict__ Wt0, const float* __restrict__ b0,
    const float* __restrict__ g0, const float* __restrict__ be0,
    const unsigned short* __restrict__ Wt1, const float* __restrict__ b1,
    const float* __restrict__ g1, const float* __restrict__ be1,
    float* __restrict__ out)
{
    __shared__ __align__(16) unsigned LDS[64 * 100];
    const int tid = threadIdx.x;
    const int node0 = blockIdx.x * 64;

    for (int i = tid; i < 64 * 96; i += 256) {
        int n = i / 96, c2 = i - n * 96;
        int gn = node0 + n;
        float2 v = make_float2(0.f, 0.f);
        if (gn < NN)
            v = (c2 < 32) ? *(const float2*)(nf + gn * 64 + 2 * c2)
                          : *(const float2*)(gat + gn * 128 + 2 * (c2 - 32));
        LDS[n * 100 + c2] = pkbf(v.x, v.y);
    }
    __syncthreads();

    const int lane = tid & 63, w = tid >> 6;
    const int c = lane & 15, ko = lane >> 4;
    const int lrow = w * 16 + 4 * ko;

    f32x4 acc[8];
    #pragma unroll
    for (int nt = 0; nt < 8; ++nt) acc[nt] = f32x4{0.f, 0.f, 0.f, 0.f};

    #pragma unroll
    for (int kb = 0; kb < 6; ++kb) {
        bf16x8 a = *(const bf16x8*)((const unsigned short*)LDS +
                                    (w * 16 + c) * 200 + kb * 32 + ko * 8);
        #pragma unroll
        for (int nt = 0; nt < 8; ++nt) {
            bf16x8 b = *(const bf16x8*)(Wt0 + (nt * 16 + c) * 192 + kb * 32 + ko * 8);
            acc[nt] = __builtin_amdgcn_mfma_f32_16x16x32_bf16(a, b, acc[nt], 0, 0, 0);
        }
    }

    float bv[8], gv[8], tv[8];
    #pragma unroll
    for (int nt = 0; nt < 8; ++nt) {
        bv[nt] = b0[nt * 16 + c];
        gv[nt] = g0[nt * 16 + c];
        tv[nt] = be0[nt * 16 + c];
    }
    __syncthreads();

    unsigned short* Hs = (unsigned short*)LDS;
    #pragma unroll
    for (int reg = 0; reg < 4; ++reg) {
        float sum = 0.f, sq = 0.f, hv[8];
        #pragma unroll
        for (int nt = 0; nt < 8; ++nt) {
            float v = acc[nt][reg] + bv[nt];
            hv[nt] = v; sum += v; sq += v * v;
        }
        #pragma unroll
        for (int m = 1; m <= 8; m <<= 1) {
            sum += __shfl_xor(sum, m, 64);
            sq  += __shfl_xor(sq, m, 64);
        }
        float mean = sum * (1.f / 128.f);
        float inv  = rsqrtf(sq * (1.f / 128.f) - mean * mean + 1e-5f);
        #pragma unroll
        for (int nt = 0; nt < 8; ++nt) {
            float h = fmaxf((hv[nt] - mean) * inv * gv[nt] + tv[nt], 0.f);
            Hs[(lrow + reg) * 136 + nt * 16 + c] = bfb(h);
        }
    }
    __syncthreads();

    #pragma unroll
    for (int nt = 0; nt < 8; ++nt) acc[nt] = f32x4{0.f, 0.f, 0.f, 0.f};
    #pragma unroll
    for (int kb = 0; kb < 4; ++kb) {
        bf16x8 a = *(const bf16x8*)((const unsigned short*)LDS +
                                    (w * 16 + c) * 136 + kb * 32 + ko * 8);
        #pragma unroll
        for (int nt = 0; nt < 8; ++nt) {
            bf16x8 b = *(const bf16x8*)(Wt1 + (nt * 16 + c) * 128 + kb * 32 + ko * 8);
            acc[nt] = __builtin_amdgcn_mfma_f32_16x16x32_bf16(a, b, acc[nt], 0, 0, 0);
        }
    }

    #pragma unroll
    for (int nt = 0; nt < 8; ++nt) {
        bv[nt] = b1[nt * 16 + c];
        gv[nt] = g1[nt * 16 + c];
        tv[nt] = be1[nt * 16 + c];
    }
    #pragma unroll
    for (int reg = 0; reg < 4; ++reg) {
        float sum = 0.f, sq = 0.f, hv[8];
        #pragma unroll
        for (int nt = 0; nt < 8; ++nt) {
            float v = acc[nt][reg] + bv[nt];
            hv[nt] = v; sum += v; sq += v * v;
        }
        #pragma unroll
        for (int m = 1; m <= 8; m <<= 1) {
            sum += __shfl_xor(sum, m, 64);
            sq  += __shfl_xor(sq, m, 64);
        }
        float mean = sum * (1.f / 128.f);
        float inv  = rsqrtf(sq * (1.f / 128.f) - mean * mean + 1e-5f);
        int row = node0 + lrow + reg;
        if (row < NN) {
            #pragma unroll
            for (int nt = 0; nt < 8; ++nt) {
                float h = fmaxf((hv[nt] - mean) * inv * gv[nt] + tv[nt], 0.f);
                int col = nt * 16 + c;
                out[row * 128 + col] = ident[row * 128 + col] + h;
            }
        }
    }
}

// ---------------------------------------------------------------------------
extern "C" void kernel_launch(void* const* d_in, const int* in_sizes, int n_in,
                              void* d_out, int out_size, void* d_ws, size_t ws_size,
                              hipStream_t stream)
{
    const float* nf       = (const float*)d_in[0];
    const float* ef       = (const float*)d_in[1];
    const int*   eidx     = (const int*)d_in[2];
    const float* W_l      = (const float*)d_in[3];
    const float* b_l      = (const float*)d_in[4];
    const float* W_r      = (const float*)d_in[5];
    const float* b_r      = (const float*)d_in[6];
    const float* W_e      = (const float*)d_in[7];
    const float* att      = (const float*)d_in[8];
    const float* gat_bias = (const float*)d_in[9];
    const float* res_W    = (const float*)d_in[10];
    const float* res_b    = (const float*)d_in[11];
    const float* res_g    = (const float*)d_in[12];
    const float* res_beta = (const float*)d_in[13];
    const float* W0       = (const float*)d_in[14];
    const float* b0       = (const float*)d_in[15];
    const float* g0       = (const float*)d_in[16];
    const float* beta0    = (const float*)d_in[17];
    const float* W1       = (const float*)d_in[18];
    const float* b1       = (const float*)d_in[19];
    const float* g1       = (const float*)d_in[20];
    const float* beta1    = (const float*)d_in[21];
    float* out = (float*)d_out;

    char* ws = (char*)d_ws;
    size_t off = 0;
    auto alloc = [&](size_t bytes) -> void* {
        void* p = ws + off;
        off += (bytes + 255) & ~(size_t)255;
        return p;
    };
    unsigned* xlp  = (unsigned*)alloc((size_t)NN * 64 * 4);   // x_l packed f16x2
    float* x_r     = (float*)alloc((size_t)NN * 128 * 4);
    float* ident   = (float*)alloc((size_t)NN * 128 * 4);
    int* deg       = (int*)alloc((size_t)NN * 4);
    int* row_start = (int*)alloc((size_t)(NN + 1) * 4);
    int* rank      = (int*)alloc((size_t)NE * 4);
    int* bsum      = (int*)alloc((size_t)(NB + 1) * 4);
    int2* csr_es   = (int2*)alloc((size_t)NE * 8);
    float* gat_out = (float*)alloc((size_t)NN * 128 * 4);
    unsigned short* Wtl   = (unsigned short*)alloc(8192 * 2);
    unsigned short* Wtr   = (unsigned short*)alloc(8192 * 2);
    unsigned short* Wtres = (unsigned short*)alloc(8192 * 2);
    unsigned short* Wt0   = (unsigned short*)alloc(24576 * 2);
    unsigned short* Wt1   = (unsigned short*)alloc(16384 * 2);
    unsigned short* Wef   = (unsigned short*)alloc(2048 * 2);

    k0_prep<<<NB, 256, 0, stream>>>(W_l, W_r, res_W, W0, W1, W_e,
                                    Wtl, Wtr, Wtres, Wt0, Wt1, Wef,
                                    deg, row_start);

    ka_nodes_degree<<<K1B + (NE + 255) / 256, 256, 0, stream>>>(
        nf, Wtl, b_l, Wtr, b_r, Wtres, res_b, res_g, res_beta,
        xlp, x_r, ident, eidx, deg, rank);

    k3a_blocksum<<<NB, 256, 0, stream>>>(deg, bsum);
    k3c_apply<<<NB, 256, 0, stream>>>(deg, bsum, row_start);

    k4_scatter<<<(NE + 255) / 256, 256, 0, stream>>>(eidx, row_start, rank, csr_es);

    k5_attn_aggregate<<<(NN * 64 + 255) / 256, 256, 0, stream>>>(
        csr_es, row_start, ef, Wef, att, xlp, x_r, gat_bias, gat_out);

    k6_mlp_mfma<<<(NN + 63) / 64, 256, 0, stream>>>(
        nf, gat_out, ident, Wt0, b0, g0, beta0, Wt1, b1, g1, beta1, out);
}

// Round 5
// 331.448 us; speedup vs baseline: 1.0606x; 1.0606x over previous
//
#include <hip/hip_runtime.h>

#define NN 50000
#define NE 800000
#define NB 196   // (NN+255)/256
#define K1B 782  // (NN+63)/64

typedef __attribute__((ext_vector_type(8))) short bf16x8;
typedef __attribute__((ext_vector_type(4))) float f32x4;
typedef __attribute__((ext_vector_type(2))) _Float16 h2f;

__device__ __forceinline__ int rfl(int v) { return __builtin_amdgcn_readfirstlane(v); }

__device__ __forceinline__ unsigned short bfb(float x) {
    union { float f; unsigned u; } v; v.f = x;
    unsigned r = v.u + 0x7FFFu + ((v.u >> 16) & 1u);
    return (unsigned short)(r >> 16);
}
__device__ __forceinline__ unsigned pkbf(float lo, float hi) {
    return ((unsigned)bfb(hi) << 16) | (unsigned)bfb(lo);
}
__device__ __forceinline__ unsigned pkh2(float a, float b) {
    union { h2f h; unsigned u; } x;
    x.h.x = (_Float16)a; x.h.y = (_Float16)b;
    return x.u;
}
__device__ __forceinline__ float fdot2u(unsigned a, unsigned b, float c) {
    union { unsigned u; h2f h; } ua, ub; ua.u = a; ub.u = b;
    return __builtin_amdgcn_fdot2(ua.h, ub.h, c, false);
}

// 16-lane sum, xor/shr DPP pattern (round-2 summation order, absmax 0.03125).
__device__ __forceinline__ float dpp_reduce16(float p) {
    int t;
    t = __builtin_amdgcn_update_dpp(0, __float_as_int(p), 0xB1, 0xF, 0xF, false);
    p += __int_as_float(t);
    t = __builtin_amdgcn_update_dpp(0, __float_as_int(p), 0x4E, 0xF, 0xF, false);
    p += __int_as_float(t);
    t = __builtin_amdgcn_update_dpp(0, __float_as_int(p), 0x124, 0xF, 0xF, false);
    p += __int_as_float(t);
    t = __builtin_amdgcn_update_dpp(0, __float_as_int(p), 0x128, 0xF, 0xF, false);
    p += __int_as_float(t);
    return p;
}

// 2^x via single v_exp_f32 (input pre-scaled by log2(e) upstream).
__device__ __forceinline__ float exp2_hw(float x) {
    float r;
    asm("v_exp_f32 %0, %1" : "=v"(r) : "v"(x));
    return r;
}

// ---------------------------------------------------------------------------
// K0 (tiny prep): bf16-transpose all weights, f16-pair W_e, zero deg, and
// statically set row_start[NN]=NE. (ef packing fused into ka's edge branch.)
// ---------------------------------------------------------------------------
__global__ __launch_bounds__(256) void k0_prep(
    const float* __restrict__ W_l, const float* __restrict__ W_r,
    const float* __restrict__ res_W, const float* __restrict__ W0,
    const float* __restrict__ W1, const float* __restrict__ W_e,
    unsigned short* __restrict__ Wtl, unsigned short* __restrict__ Wtr,
    unsigned short* __restrict__ Wtres, unsigned short* __restrict__ Wt0,
    unsigned short* __restrict__ Wt1,
    unsigned* __restrict__ Wep,
    int* __restrict__ deg, int* __restrict__ row_start)
{
    const int t0 = blockIdx.x * 256 + threadIdx.x;
    if (t0 < 24576) { int n = t0 / 192, k = t0 - n * 192; Wt0[t0] = bfb(W0[k * 128 + n]); }
    if (t0 < 16384) { int n = t0 >> 7, k = t0 & 127; Wt1[t0] = bfb(W1[k * 128 + n]); }
    if (t0 < 8192) {
        int n = t0 >> 6, k = t0 & 63;
        Wtl[t0]   = bfb(W_l[k * 128 + n]);
        Wtr[t0]   = bfb(W_r[k * 128 + n]);
        Wtres[t0] = bfb(res_W[k * 128 + n]);
    }
    if (t0 < 1024) {  // Wep[c][j] = (W_e[2j][c], W_e[2j+1][c])
        int c = t0 >> 3, j = t0 & 7;
        Wep[t0] = pkh2(W_e[(2 * j) * 128 + c], W_e[(2 * j + 1) * 128 + c]);
    }
    if (t0 < NN) deg[t0] = 0;
    if (t0 == 0) row_start[NN] = NE;
}

// ---------------------------------------------------------------------------
// KA (fused): blocks [0,K1B) do the MFMA node transforms (x_l -> packed f16,
// x_r, ident); blocks [K1B, ...) do degree count + per-edge rank AND pack
// this edge's features f32->f16 (sequential 64B read / 32B write overlaps
// under the random-atomic latency).
// ---------------------------------------------------------------------------
__global__ __launch_bounds__(256, 4) void ka_nodes_degree(
    const float* __restrict__ nf,
    const unsigned short* __restrict__ Wtl, const float* __restrict__ b_l,
    const unsigned short* __restrict__ Wtr, const float* __restrict__ b_r,
    const unsigned short* __restrict__ Wtres, const float* __restrict__ res_b,
    const float* __restrict__ res_g, const float* __restrict__ res_beta,
    unsigned* __restrict__ xlp, float* __restrict__ x_r, float* __restrict__ ident,
    const int* __restrict__ eidx, int* __restrict__ deg, int* __restrict__ rank,
    const float* __restrict__ ef, unsigned* __restrict__ efp)
{
    if (blockIdx.x >= K1B) {
        int e = (blockIdx.x - K1B) * 256 + threadIdx.x;
        if (e < NE) {
            rank[e] = atomicAdd(deg + eidx[NE + e], 1);
            const float4* er = (const float4*)(ef + (size_t)e * 16);
            float4 v0 = er[0], v1 = er[1], v2 = er[2], v3 = er[3];
            uint4 o0, o1;
            o0.x = pkh2(v0.x, v0.y); o0.y = pkh2(v0.z, v0.w);
            o0.z = pkh2(v1.x, v1.y); o0.w = pkh2(v1.z, v1.w);
            o1.x = pkh2(v2.x, v2.y); o1.y = pkh2(v2.z, v2.w);
            o1.z = pkh2(v3.x, v3.y); o1.w = pkh2(v3.z, v3.w);
            *(uint4*)(efp + (size_t)e * 8)     = o0;
            *(uint4*)(efp + (size_t)e * 8 + 4) = o1;
        }
        return;
    }
    __shared__ __align__(16) unsigned As32[64 * 36];
    const int tid = threadIdx.x;
    const int node0 = blockIdx.x * 64;

    for (int i = tid; i < 64 * 32; i += 256) {
        int n = i >> 5, c2 = i & 31;
        int gn = node0 + n;
        float2 v = make_float2(0.f, 0.f);
        if (gn < NN) v = *(const float2*)(nf + gn * 64 + 2 * c2);
        As32[n * 36 + c2] = pkbf(v.x, v.y);
    }
    __syncthreads();

    const int lane = tid & 63, w = tid >> 6;
    const int c = lane & 15, ko = lane >> 4;
    const unsigned short* As = (const unsigned short*)As32;
    bf16x8 a0 = *(const bf16x8*)(As + (w * 16 + c) * 72 + 0 * 32 + ko * 8);
    bf16x8 a1 = *(const bf16x8*)(As + (w * 16 + c) * 72 + 1 * 32 + ko * 8);
    const int lrow0 = node0 + w * 16 + 4 * ko;

    #pragma unroll
    for (int p = 0; p < 3; ++p) {
        const unsigned short* Wt = (p == 0) ? Wtl : (p == 1) ? Wtr : Wtres;
        f32x4 acc[8];
        #pragma unroll
        for (int nt = 0; nt < 8; ++nt) acc[nt] = f32x4{0.f, 0.f, 0.f, 0.f};
        #pragma unroll
        for (int nt = 0; nt < 8; ++nt) {
            bf16x8 bf0 = *(const bf16x8*)(Wt + (nt * 16 + c) * 64 + 0 * 32 + ko * 8);
            acc[nt] = __builtin_amdgcn_mfma_f32_16x16x32_bf16(a0, bf0, acc[nt], 0, 0, 0);
            bf16x8 bf1 = *(const bf16x8*)(Wt + (nt * 16 + c) * 64 + 1 * 32 + ko * 8);
            acc[nt] = __builtin_amdgcn_mfma_f32_16x16x32_bf16(a1, bf1, acc[nt], 0, 0, 0);
        }
        if (p == 0) {
            // x_l: pack channel pairs (2k, 2k+1) to f16x2. Pair partners live
            // in lane^1 (c and c^1); even-c lanes store 4B each.
            float bv[8];
            #pragma unroll
            for (int nt = 0; nt < 8; ++nt) bv[nt] = b_l[nt * 16 + c];
            #pragma unroll
            for (int reg = 0; reg < 4; ++reg) {
                int row = lrow0 + reg;
                #pragma unroll
                for (int nt = 0; nt < 8; ++nt) {
                    float v = acc[nt][reg] + bv[nt];
                    float v2 = __shfl_xor(v, 1, 64);
                    if (row < NN && (lane & 1) == 0)
                        xlp[row * 64 + nt * 8 + (c >> 1)] = pkh2(v, v2);
                }
            }
        } else if (p == 1) {
            float bv[8];
            #pragma unroll
            for (int nt = 0; nt < 8; ++nt) bv[nt] = b_r[nt * 16 + c];
            #pragma unroll
            for (int reg = 0; reg < 4; ++reg) {
                int row = lrow0 + reg;
                if (row < NN) {
                    #pragma unroll
                    for (int nt = 0; nt < 8; ++nt)
                        x_r[row * 128 + nt * 16 + c] = acc[nt][reg] + bv[nt];
                }
            }
        } else {
            float bv[8], gv[8], tv[8];
            #pragma unroll
            for (int nt = 0; nt < 8; ++nt) {
                bv[nt] = res_b[nt * 16 + c];
                gv[nt] = res_g[nt * 16 + c];
                tv[nt] = res_beta[nt * 16 + c];
            }
            #pragma unroll
            for (int reg = 0; reg < 4; ++reg) {
                float sum = 0.f, sq = 0.f, hv[8];
                #pragma unroll
                for (int nt = 0; nt < 8; ++nt) {
                    float v = acc[nt][reg] + bv[nt];
                    hv[nt] = v; sum += v; sq += v * v;
                }
                #pragma unroll
                for (int m = 1; m <= 8; m <<= 1) {
                    sum += __shfl_xor(sum, m, 64);
                    sq  += __shfl_xor(sq, m, 64);
                }
                float mean = sum * (1.f / 128.f);
                float inv  = rsqrtf(sq * (1.f / 128.f) - mean * mean + 1e-5f);
                int row = lrow0 + reg;
                if (row < NN) {
                    #pragma unroll
                    for (int nt = 0; nt < 8; ++nt)
                        ident[row * 128 + nt * 16 + c] =
                            (hv[nt] - mean) * inv * gv[nt] + tv[nt];
                }
            }
        }
    }
}

// ---------------------------------------------------------------------------
// K3a: per-block degree sums.
// ---------------------------------------------------------------------------
__global__ __launch_bounds__(256) void k3a_blocksum(
    const int* __restrict__ deg, int* __restrict__ bsum)
{
    __shared__ int ws[4];
    int i = blockIdx.x * 256 + threadIdx.x;
    int v = (i < NN) ? deg[i] : 0;
    #pragma unroll
    for (int m = 32; m >= 1; m >>= 1) v += __shfl_xor(v, m, 64);
    if ((threadIdx.x & 63) == 0) ws[threadIdx.x >> 6] = v;
    __syncthreads();
    if (threadIdx.x == 0) bsum[blockIdx.x] = ws[0] + ws[1] + ws[2] + ws[3];
}

// ---------------------------------------------------------------------------
// K3c: block-local scan + prefix of bsum -> row_start.
// ---------------------------------------------------------------------------
__global__ __launch_bounds__(256) void k3c_apply(
    const int* __restrict__ deg, const int* __restrict__ bsum,
    int* __restrict__ row_start)
{
    __shared__ int wsum[4];
    __shared__ int roff[4];
    const int tid = threadIdx.x, lane = tid & 63, wid = tid >> 6;
    int bv = (tid < blockIdx.x) ? bsum[tid] : 0;   // blockIdx.x <= 195 < 256
    #pragma unroll
    for (int m = 32; m >= 1; m >>= 1) bv += __shfl_xor(bv, m, 64);
    if (lane == 0) roff[wid] = bv;

    int i = blockIdx.x * 256 + tid;
    int v = (i < NN) ? deg[i] : 0;
    int sc = v;
    #pragma unroll
    for (int m = 1; m < 64; m <<= 1) {
        int t = __shfl_up(sc, m, 64);
        if (lane >= m) sc += t;
    }
    if (lane == 63) wsum[wid] = sc;
    __syncthreads();
    int off = roff[0] + roff[1] + roff[2] + roff[3];
    for (int w = 0; w < wid; ++w) off += wsum[w];
    int excl = off + sc - v;
    if (i < NN) row_start[i] = excl;
}

// ---------------------------------------------------------------------------
// K4: pure scatter (no atomics): pos = row_start[dst] + rank[e].
// ---------------------------------------------------------------------------
__global__ __launch_bounds__(256) void k4_scatter(
    const int* __restrict__ eidx, const int* __restrict__ row_start,
    const int* __restrict__ rank, int2* __restrict__ csr_es)
{
    int e = blockIdx.x * 256 + threadIdx.x;
    if (e >= NE) return;
    int dst = eidx[NE + e];
    csr_es[row_start[dst] + rank[e]] = make_int2(e, eidx[e]);
}

// ---------------------------------------------------------------------------
// K5: fused GATv2 attention + aggregation. One wave per node.
// Chunked CSR preload: one coalesced csr_es load per <=64-edge chunk; per
// edge, (eid, src) come from v_readlane -> SGPRs, so ef loads are uniform
// (scalar-side) and the xlp gather uses saddr form. Depth-6 rotating
// pipeline (~350cy cover for the random xlp gather). exp via v_exp_f32
// (att pre-scaled by log2 e). Round-2 xor-DPP logit reduce.
// ---------------------------------------------------------------------------
__global__ __launch_bounds__(256, 4) void k5_attn_aggregate(
    const int2* __restrict__ csr_es, const int* __restrict__ row_start,
    const unsigned* __restrict__ efp, const unsigned* __restrict__ Wep,
    const float* __restrict__ att,
    const unsigned* __restrict__ xlp, const float* __restrict__ x_r,
    const float* __restrict__ gat_bias,
    float* __restrict__ gat_out)
{
    const int lane = threadIdx.x & 63;
    const int node = (blockIdx.x * 256 + threadIdx.x) >> 6;
    if (node >= NN) return;
    const int c = lane * 2;

    uint4 t0 = *(const uint4*)(Wep + c * 8);
    uint4 t1 = *(const uint4*)(Wep + c * 8 + 4);
    uint4 t2 = *(const uint4*)(Wep + (c + 1) * 8);
    uint4 t3 = *(const uint4*)(Wep + (c + 1) * 8 + 4);
    unsigned wx0 = t0.x, wx1 = t0.y, wx2 = t0.z, wx3 = t0.w;
    unsigned wx4 = t1.x, wx5 = t1.y, wx6 = t1.z, wx7 = t1.w;
    unsigned wy0 = t2.x, wy1 = t2.y, wy2 = t2.z, wy3 = t2.w;
    unsigned wy4 = t3.x, wy5 = t3.y, wy6 = t3.z, wy7 = t3.w;

    const float LOG2E = 1.44269504088896340736f;
    float2 a2 = *(const float2*)(att + c);
    a2.x *= LOG2E; a2.y *= LOG2E;
    const float2 xr = *(const float2*)(x_r + node * 128 + c);
    const uint4* __restrict__ efq = (const uint4*)efp;
    const unsigned* __restrict__ xlc = xlp + lane;

    const int sj  = rfl(row_start[node]);
    const int epj = rfl(row_start[node + 1]);

    float den = 0.f, n0 = 0.f, n1 = 0.f;

    for (int base = sj; base < epj; base += 64) {
        const int cnt = min(64, epj - base);
        int pidx = base + lane; if (pidx > NE - 1) pidx = NE - 1;
        const int2 mc = csr_es[pidx];   // coalesced: this chunk's (eid, src)

        uint4 aE0, aE1, bE0, bE1, cE0, cE1, dE0, dE1, eE0, eE1, fE0, fE1;
        unsigned aX, bX, cX, dX, eX, fX;

#define LOADS(E0_, E1_, X_, K_)                                            \
        { int kk = (K_); if (kk >= cnt) kk = cnt - 1;                      \
          int eid  = __builtin_amdgcn_readlane(mc.x, kk);                  \
          int srcn = __builtin_amdgcn_readlane(mc.y, kk);                  \
          E0_ = efq[eid * 2 + 0]; E1_ = efq[eid * 2 + 1];                  \
          X_  = xlc[srcn * 64]; }

#define CONSUME(E0_, E1_, X_)                                              \
        { asm volatile("" : "+v"(wx0), "+v"(wx1), "+v"(wx2), "+v"(wx3),    \
                            "+v"(wx4), "+v"(wx5), "+v"(wx6), "+v"(wx7));   \
          asm volatile("" : "+v"(wy0), "+v"(wy1), "+v"(wy2), "+v"(wy3),    \
                            "+v"(wy4), "+v"(wy5), "+v"(wy6), "+v"(wy7));   \
          union { unsigned u; h2f h; } ux; ux.u = (X_);                    \
          float cx0 = (float)ux.h.x, cx1 = (float)ux.h.y;                  \
          float ax = cx0 + xr.x;                                           \
          float ay = cx1 + xr.y;                                           \
          float bx = 0.f, by = 0.f;                                        \
          ax = fdot2u((E0_).x, wx0, ax);  ay = fdot2u((E0_).x, wy0, ay);   \
          bx = fdot2u((E0_).y, wx1, bx);  by = fdot2u((E0_).y, wy1, by);   \
          ax = fdot2u((E0_).z, wx2, ax);  ay = fdot2u((E0_).z, wy2, ay);   \
          bx = fdot2u((E0_).w, wx3, bx);  by = fdot2u((E0_).w, wy3, by);   \
          ax = fdot2u((E1_).x, wx4, ax);  ay = fdot2u((E1_).x, wy4, ay);   \
          bx = fdot2u((E1_).y, wx5, bx);  by = fdot2u((E1_).y, wy5, by);   \
          ax = fdot2u((E1_).z, wx6, ax);  ay = fdot2u((E1_).z, wy6, ay);   \
          bx = fdot2u((E1_).w, wx7, bx);  by = fdot2u((E1_).w, wy7, by);   \
          float evx = ax + bx;                                             \
          float evy = ay + by;                                             \
          float lx = fmaxf(evx, 0.2f * evx);                               \
          float ly = fmaxf(evy, 0.2f * evy);                               \
          float p = lx * a2.x + ly * a2.y;                                 \
          p = dpp_reduce16(p);                                             \
          float ev = exp2_hw(p);                                           \
          den += ev; n0 += ev * cx0; n1 += ev * cx1; }

        LOADS(aE0, aE1, aX, 0);
        LOADS(bE0, bE1, bX, 1);
        LOADS(cE0, cE1, cX, 2);
        LOADS(dE0, dE1, dX, 3);
        LOADS(eE0, eE1, eX, 4);
        int j = 0;
        while (j + 6 <= cnt) {
            LOADS(fE0, fE1, fX, j + 5);
            CONSUME(aE0, aE1, aX);
            LOADS(aE0, aE1, aX, j + 6);
            CONSUME(bE0, bE1, bX);
            LOADS(bE0, bE1, bX, j + 7);
            CONSUME(cE0, cE1, cX);
            LOADS(cE0, cE1, cX, j + 8);
            CONSUME(dE0, dE1, dX);
            LOADS(dE0, dE1, dX, j + 9);
            CONSUME(eE0, eE1, eX);
            LOADS(eE0, eE1, eX, j + 10);
            CONSUME(fE0, fE1, fX);
            j += 6;
        }
        if (j < cnt)     CONSUME(aE0, aE1, aX);
        if (j + 1 < cnt) CONSUME(bE0, bE1, bX);
        if (j + 2 < cnt) CONSUME(cE0, cE1, cX);
        if (j + 3 < cnt) CONSUME(dE0, dE1, dX);
        if (j + 4 < cnt) CONSUME(eE0, eE1, eX);
#undef LOADS
#undef CONSUME
    }
    float rden = (den > 0.f) ? (1.f / den) : 0.f;
    float2 gb = *(const float2*)(gat_bias + c);
    float2 o; o.x = n0 * rden + gb.x; o.y = n1 * rden + gb.y;
    *(float2*)(gat_out + node * 128 + c) = o;
}

// ---------------------------------------------------------------------------
// K6 (MFMA): MLP + LN + residual add.  (unchanged)
// ---------------------------------------------------------------------------
__global__ __launch_bounds__(256, 4) void k6_mlp_mfma(
    const float* __restrict__ nf, const float* __restrict__ gat,
    const float* __restrict__ ident,
    const unsigned short* __restrict__ Wt0, const float* __restrict__ b0,
    const float* __restrict__ g0, const float* __restrict__ be0,
    const unsigned short* __restrict__ Wt1, const float* __restrict__ b1,
    const float* __restrict__ g1, const float* __restrict__ be1,
    float* __restrict__ out)
{
    __shared__ __align__(16) unsigned LDS[64 * 100];
    const int tid = threadIdx.x;
    const int node0 = blockIdx.x * 64;

    for (int i = tid; i < 64 * 96; i += 256) {
        int n = i / 96, c2 = i - n * 96;
        int gn = node0 + n;
        float2 v = make_float2(0.f, 0.f);
        if (gn < NN)
            v = (c2 < 32) ? *(const float2*)(nf + gn * 64 + 2 * c2)
                          : *(const float2*)(gat + gn * 128 + 2 * (c2 - 32));
        LDS[n * 100 + c2] = pkbf(v.x, v.y);
    }
    __syncthreads();

    const int lane = tid & 63, w = tid >> 6;
    const int c = lane & 15, ko = lane >> 4;
    const int lrow = w * 16 + 4 * ko;

    f32x4 acc[8];
    #pragma unroll
    for (int nt = 0; nt < 8; ++nt) acc[nt] = f32x4{0.f, 0.f, 0.f, 0.f};

    #pragma unroll
    for (int kb = 0; kb < 6; ++kb) {
        bf16x8 a = *(const bf16x8*)((const unsigned short*)LDS +
                                    (w * 16 + c) * 200 + kb * 32 + ko * 8);
        #pragma unroll
        for (int nt = 0; nt < 8; ++nt) {
            bf16x8 b = *(const bf16x8*)(Wt0 + (nt * 16 + c) * 192 + kb * 32 + ko * 8);
            acc[nt] = __builtin_amdgcn_mfma_f32_16x16x32_bf16(a, b, acc[nt], 0, 0, 0);
        }
    }

    float bv[8], gv[8], tv[8];
    #pragma unroll
    for (int nt = 0; nt < 8; ++nt) {
        bv[nt] = b0[nt * 16 + c];
        gv[nt] = g0[nt * 16 + c];
        tv[nt] = be0[nt * 16 + c];
    }
    __syncthreads();

    unsigned short* Hs = (unsigned short*)LDS;
    #pragma unroll
    for (int reg = 0; reg < 4; ++reg) {
        float sum = 0.f, sq = 0.f, hv[8];
        #pragma unroll
        for (int nt = 0; nt < 8; ++nt) {
            float v = acc[nt][reg] + bv[nt];
            hv[nt] = v; sum += v; sq += v * v;
        }
        #pragma unroll
        for (int m = 1; m <= 8; m <<= 1) {
            sum += __shfl_xor(sum, m, 64);
            sq  += __shfl_xor(sq, m, 64);
        }
        float mean = sum * (1.f / 128.f);
        float inv  = rsqrtf(sq * (1.f / 128.f) - mean * mean + 1e-5f);
        #pragma unroll
        for (int nt = 0; nt < 8; ++nt) {
            float h = fmaxf((hv[nt] - mean) * inv * gv[nt] + tv[nt], 0.f);
            Hs[(lrow + reg) * 136 + nt * 16 + c] = bfb(h);
        }
    }
    __syncthreads();

    #pragma unroll
    for (int nt = 0; nt < 8; ++nt) acc[nt] = f32x4{0.f, 0.f, 0.f, 0.f};
    #pragma unroll
    for (int kb = 0; kb < 4; ++kb) {
        bf16x8 a = *(const bf16x8*)((const unsigned short*)LDS +
                                    (w * 16 + c) * 136 + kb * 32 + ko * 8);
        #pragma unroll
        for (int nt = 0; nt < 8; ++nt) {
            bf16x8 b = *(const bf16x8*)(Wt1 + (nt * 16 + c) * 128 + kb * 32 + ko * 8);
            acc[nt] = __builtin_amdgcn_mfma_f32_16x16x32_bf16(a, b, acc[nt], 0, 0, 0);
        }
    }

    #pragma unroll
    for (int nt = 0; nt < 8; ++nt) {
        bv[nt] = b1[nt * 16 + c];
        gv[nt] = g1[nt * 16 + c];
        tv[nt] = be1[nt * 16 + c];
    }
    #pragma unroll
    for (int reg = 0; reg < 4; ++reg) {
        float sum = 0.f, sq = 0.f, hv[8];
        #pragma unroll
        for (int nt = 0; nt < 8; ++nt) {
            float v = acc[nt][reg] + bv[nt];
            hv[nt] = v; sum += v; sq += v * v;
        }
        #pragma unroll
        for (int m = 1; m <= 8; m <<= 1) {
            sum += __shfl_xor(sum, m, 64);
            sq  += __shfl_xor(sq, m, 64);
        }
        float mean = sum * (1.f / 128.f);
        float inv  = rsqrtf(sq * (1.f / 128.f) - mean * mean + 1e-5f);
        int row = node0 + lrow + reg;
        if (row < NN) {
            #pragma unroll
            for (int nt = 0; nt < 8; ++nt) {
                float h = fmaxf((hv[nt] - mean) * inv * gv[nt] + tv[nt], 0.f);
                int col = nt * 16 + c;
                out[row * 128 + col] = ident[row * 128 + col] + h;
            }
        }
    }
}

// ---------------------------------------------------------------------------
extern "C" void kernel_launch(void* const* d_in, const int* in_sizes, int n_in,
                              void* d_out, int out_size, void* d_ws, size_t ws_size,
                              hipStream_t stream)
{
    const float* nf       = (const float*)d_in[0];
    const float* ef       = (const float*)d_in[1];
    const int*   eidx     = (const int*)d_in[2];
    const float* W_l      = (const float*)d_in[3];
    const float* b_l      = (const float*)d_in[4];
    const float* W_r      = (const float*)d_in[5];
    const float* b_r      = (const float*)d_in[6];
    const float* W_e      = (const float*)d_in[7];
    const float* att      = (const float*)d_in[8];
    const float* gat_bias = (const float*)d_in[9];
    const float* res_W    = (const float*)d_in[10];
    const float* res_b    = (const float*)d_in[11];
    const float* res_g    = (const float*)d_in[12];
    const float* res_beta = (const float*)d_in[13];
    const float* W0       = (const float*)d_in[14];
    const float* b0       = (const float*)d_in[15];
    const float* g0       = (const float*)d_in[16];
    const float* beta0    = (const float*)d_in[17];
    const float* W1       = (const float*)d_in[18];
    const float* b1       = (const float*)d_in[19];
    const float* g1       = (const float*)d_in[20];
    const float* beta1    = (const float*)d_in[21];
    float* out = (float*)d_out;

    char* ws = (char*)d_ws;
    size_t off = 0;
    auto alloc = [&](size_t bytes) -> void* {
        void* p = ws + off;
        off += (bytes + 255) & ~(size_t)255;
        return p;
    };
    unsigned* xlp  = (unsigned*)alloc((size_t)NN * 64 * 4);   // x_l packed f16x2
    float* x_r     = (float*)alloc((size_t)NN * 128 * 4);
    float* ident   = (float*)alloc((size_t)NN * 128 * 4);
    int* deg       = (int*)alloc((size_t)NN * 4);
    int* row_start = (int*)alloc((size_t)(NN + 1) * 4);
    int* rank      = (int*)alloc((size_t)NE * 4);
    int* bsum      = (int*)alloc((size_t)(NB + 1) * 4);
    int2* csr_es   = (int2*)alloc((size_t)NE * 8);
    float* gat_out = (float*)alloc((size_t)NN * 128 * 4);
    unsigned short* Wtl   = (unsigned short*)alloc(8192 * 2);
    unsigned short* Wtr   = (unsigned short*)alloc(8192 * 2);
    unsigned short* Wtres = (unsigned short*)alloc(8192 * 2);
    unsigned short* Wt0   = (unsigned short*)alloc(24576 * 2);
    unsigned short* Wt1   = (unsigned short*)alloc(16384 * 2);
    unsigned* Wep = (unsigned*)alloc(1024 * 4);
    unsigned* efp = (unsigned*)alloc((size_t)NE * 8 * 4);

    k0_prep<<<NB, 256, 0, stream>>>(W_l, W_r, res_W, W0, W1, W_e,
                                    Wtl, Wtr, Wtres, Wt0, Wt1, Wep,
                                    deg, row_start);

    ka_nodes_degree<<<K1B + (NE + 255) / 256, 256, 0, stream>>>(
        nf, Wtl, b_l, Wtr, b_r, Wtres, res_b, res_g, res_beta,
        xlp, x_r, ident, eidx, deg, rank, ef, efp);

    k3a_blocksum<<<NB, 256, 0, stream>>>(deg, bsum);
    k3c_apply<<<NB, 256, 0, stream>>>(deg, bsum, row_start);

    k4_scatter<<<(NE + 255) / 256, 256, 0, stream>>>(eidx, row_start, rank, csr_es);

    k5_attn_aggregate<<<(NN * 64 + 255) / 256, 256, 0, stream>>>(
        csr_es, row_start, efp, Wep, att, xlp, x_r, gat_bias, gat_out);

    k6_mlp_mfma<<<(NN + 63) / 64, 256, 0, stream>>>(
        nf, gat_out, ident, Wt0, b0, g0, beta0, Wt1, b1, g1, beta1, out);
}